// Round 5
// baseline (272.748 us; speedup 1.0000x reference)
//
#include <hip/hip_runtime.h>
#include <cstdint>
#include <math.h>

// MHA: B=2, S=2048, D_MODEL=1024, H=16, D_HEAD=64.
// fused cvt (fp32->bf16, W transposed) -> fused QKV GEMM (bf16 MFMA, dbuf
// prefetch-after-barrier) -> flash attention (32x32x16 MFMA, S^T layout,
// no-max exp2 softmax, key-split) -> final GEMM (dbuf, fp32 out).

typedef __bf16 bf16;
typedef __bf16 bf16x2 __attribute__((ext_vector_type(2)));
typedef __bf16 bf16x4 __attribute__((ext_vector_type(4)));
typedef __bf16 bf16x8 __attribute__((ext_vector_type(8)));
typedef float f32x4 __attribute__((ext_vector_type(4)));
typedef float f32x16 __attribute__((ext_vector_type(16)));
typedef unsigned u32x4 __attribute__((ext_vector_type(4)));

__device__ __forceinline__ void gl2lds16(const void* g, void* l) {
  __builtin_amdgcn_global_load_lds(
      (const __attribute__((address_space(1))) unsigned int*)g,
      (__attribute__((address_space(3))) unsigned int*)l,
      16, 0, 0);
}

__device__ __forceinline__ unsigned pkbf(float a, float b) {
  bf16x2 t;
  t[0] = (bf16)a;
  t[1] = (bf16)b;
  return __builtin_bit_cast(unsigned, t);
}

// ---------------- fused conversions (one launch) ----------------
// by 0-2: q/k/v fp32->bf16 (4 elem/thread); by 3-5: Wq/Wk/Wv transpose;
// by 6: Wo transpose.
__global__ __launch_bounds__(256) void k_cvt(const float* __restrict__ q,
                                             const float* __restrict__ k,
                                             const float* __restrict__ v,
                                             const float* __restrict__ Wq,
                                             const float* __restrict__ Wk,
                                             const float* __restrict__ Wv,
                                             const float* __restrict__ Wo,
                                             bf16* __restrict__ qkv,
                                             bf16* __restrict__ WqkvT,
                                             bf16* __restrict__ WoT) {
  const int by = blockIdx.y;
  if (by < 3) {
    const float* in = by == 0 ? q : (by == 1 ? k : v);
    bf16* out = qkv + (size_t)by * 4194304;
    const size_t i = ((size_t)blockIdx.x * 256 + threadIdx.x) * 4;
    const float4 vv = *(const float4*)(in + i);
    bf16x4 o;
    o[0] = (bf16)vv.x; o[1] = (bf16)vv.y; o[2] = (bf16)vv.z; o[3] = (bf16)vv.w;
    *(bf16x4*)(out + i) = o;
  } else if (by < 6) {
    const float* W = by == 3 ? Wq : (by == 4 ? Wk : Wv);
    bf16* out = WqkvT + (size_t)(by - 3) * 1048576;
    const int idx = blockIdx.x * 256 + threadIdx.x;  // 1M
    const int n = idx >> 10, d = idx & 1023;
    out[idx] = (bf16)W[((n >> 6) << 16) + (d << 6) + (n & 63)];
  } else {
    const int idx = blockIdx.x * 256 + threadIdx.x;  // 1M
    const int n = idx >> 10, kk = idx & 1023;
    WoT[idx] = (bf16)Wo[(kk << 10) + n];
  }
}

// ---------------- fused QKV GEMM: M=4096, K=1024, N=3072, dbuf ----------------
__global__ __launch_bounds__(256) void k_gemm_qkv(const bf16* __restrict__ Abase,
                                                  const bf16* __restrict__ Bt,
                                                  const float* __restrict__ bq,
                                                  const float* __restrict__ bk,
                                                  const float* __restrict__ bv,
                                                  bf16* __restrict__ Qh,
                                                  bf16* __restrict__ Kh,
                                                  bf16* __restrict__ Vt) {
  __shared__ __align__(16) bf16 Alds[2][4096];
  __shared__ __align__(16) bf16 Blds[2][4096];
  const int t = threadIdx.x;
  const int w = t >> 6;
  const int lane = t & 63;
  const int lane15 = lane & 15;
  const int quad = lane >> 4;
  const int wm = w >> 1, wn = w & 1;
  const int mb = blockIdx.x, nb = blockIdx.y;
  const int sel = nb >> 3;  // 0=Q,1=K,2=V (uniform per block)

  const bf16* A = Abase + (size_t)sel * 4194304;
  const int ms = t & 127;
  const int c0 = t >> 7;
  const bf16* Ag = A + (size_t)(mb * 128 + ms) * 1024 + c0 * 8;
  const bf16* Bg = Bt + (size_t)(nb * 128 + ms) * 1024 + c0 * 8;
  const int d0 = w * 512, d1 = 2048 + w * 512;

  // prologue: stage tile k0=0 into buffer 0
  gl2lds16(Ag, &Alds[0][d0]);
  gl2lds16(Ag + 16, &Alds[0][d1]);
  gl2lds16(Bg, &Blds[0][d0]);
  gl2lds16(Bg + 16, &Blds[0][d1]);

  f32x4 acc[4][4] = {};

  for (int k0 = 0; k0 < 1024; k0 += 32) {
    const int b = (k0 >> 5) & 1;
    __syncthreads();  // buffer b ready; prev reads of buf b^1 done
    if (k0 < 992) {
      const bf16* An = Ag + k0 + 32;
      const bf16* Bn = Bg + k0 + 32;
      bf16* Ab = Alds[b ^ 1];
      bf16* Bb = Blds[b ^ 1];
      gl2lds16(An, Ab + d0);
      gl2lds16(An + 16, Ab + d1);
      gl2lds16(Bn, Bb + d0);
      gl2lds16(Bn + 16, Bb + d1);
    }
    const bf16* Abuf = Alds[b];
    const bf16* Bbuf = Blds[b];
    bf16x8 af[4], bfr[4];
#pragma unroll
    for (int i = 0; i < 4; ++i)
      af[i] = *(const bf16x8*)(Abuf + (quad * 128 + wm * 64 + i * 16 + lane15) * 8);
#pragma unroll
    for (int j = 0; j < 4; ++j)
      bfr[j] = *(const bf16x8*)(Bbuf + (quad * 128 + wn * 64 + j * 16 + lane15) * 8);
#pragma unroll
    for (int i = 0; i < 4; ++i)
#pragma unroll
      for (int j = 0; j < 4; ++j)
        acc[i][j] = __builtin_amdgcn_mfma_f32_16x16x32_bf16(af[i], bfr[j], acc[i][j], 0, 0, 0);
  }

  // scale Q by 0.125*log2(e) so attention can use exp2 directly
  const float scale = sel == 0 ? 0.18033688011112042f : 1.0f;
  const float* bias = sel == 0 ? bq : (sel == 1 ? bk : bv);
  const int nb2 = nb & 7;
  const int mbase = mb * 128 + wm * 64;
  const int nbase = nb2 * 128 + wn * 64;
  if (sel < 2) {
    bf16* outp = sel == 0 ? Qh : Kh;
#pragma unroll
    for (int j = 0; j < 4; ++j) {
      const int n = nbase + j * 16 + lane15;  // 0..1023
      const float bvl = bias[n];
      const int h = n >> 6, e = n & 63;
#pragma unroll
      for (int i = 0; i < 4; ++i) {
#pragma unroll
        for (int r = 0; r < 4; ++r) {
          const int m = mbase + i * 16 + quad * 4 + r;
          const float vv = (acc[i][j][r] + bvl) * scale;
          const int b = m >> 11, s = m & 2047;
          outp[(size_t)(b * 16 + h) * 131072 + s * 64 + e] = (bf16)vv;
        }
      }
    }
  } else {
    // V transposed [b,h,e,s]: r -> s contiguous, pack bf16x4 (8B) stores
#pragma unroll
    for (int j = 0; j < 4; ++j) {
      const int n = nbase + j * 16 + lane15;
      const float bvl = bias[n];
      const int h = n >> 6, e = n & 63;
#pragma unroll
      for (int i = 0; i < 4; ++i) {
        const int m = mbase + i * 16 + quad * 4;
        const int b = m >> 11, s = m & 2047;
        bf16x4 o;
#pragma unroll
        for (int r = 0; r < 4; ++r) o[r] = (bf16)(acc[i][j][r] + bvl);
        *(bf16x4*)(Vt + (size_t)(b * 16 + h) * 131072 + e * 2048 + s) = o;
      }
    }
  }
}

// ---------------- flash attention (unchanged from round 4) ----------------
__global__ __launch_bounds__(512, 4) void k_attn(const bf16* __restrict__ Qh,
                                                 const bf16* __restrict__ Kh,
                                                 const bf16* __restrict__ Vt,
                                                 bf16* __restrict__ attn) {
  __shared__ __align__(16) bf16 lds[32768];  // 64 KiB
  const int t = threadIdx.x;
  const int w = t >> 6;        // 0..7
  const int lane = t & 63;
  const int lane31 = lane & 31;
  const int hi = lane >> 5;
  const int bh = blockIdx.y;
  const bf16* Qp = Qh + (size_t)bh * 131072;
  const bf16* Kp = Kh + (size_t)bh * 131072;
  const bf16* Vp = Vt + (size_t)bh * 131072;
  const int h = w >> 2;        // key-half
  const int q0 = blockIdx.x * 128 + (w & 3) * 32;

  bf16x8 aq[4];
#pragma unroll
  for (int kc = 0; kc < 4; ++kc)
    aq[kc] = *(const bf16x8*)(Qp + (size_t)(q0 + lane31) * 64 + kc * 16 + hi * 8);

  int raddr[4];
#pragma unroll
  for (int cc = 0; cc < 4; ++cc)
    raddr[cc] = lane31 * 64 + (((cc * 2 + hi + lane31) & 7) << 3);

  const bf16* kg[2];
  const bf16* vg[2];
  int kdst[2], vdst[2];
#pragma unroll
  for (int i = 0; i < 2; ++i) {
    const int cid = w * 2 + i;                   // 0..15
    const int half = cid >> 3;
    const int sl = ((cid & 7) << 6) + lane;      // 0..511 within half
    const int row = sl >> 3;
    const int c = ((sl & 7) - row) & 7;
    kg[i] = Kp + ((size_t)(half << 10) + row) * 64 + c * 8;
    vg[i] = Vp + (size_t)row * 2048 + (half << 10) + c * 8;
    kdst[i] = (half << 14) + ((cid & 7) << 9);
    vdst[i] = kdst[i] + 8192;
  }

  f32x16 O[2] = {};
  float l_ = 0.f;

#pragma unroll
  for (int i = 0; i < 2; ++i) {
    gl2lds16(kg[i], lds + kdst[i]);
    gl2lds16(vg[i], lds + vdst[i]);
  }

#pragma unroll 2
  for (int it = 0; it < 16; ++it) {
    const int bufo = (it & 1) << 12;
    __syncthreads();
    if (it + 1 < 16) {
      const int po = bufo ^ 4096;
#pragma unroll
      for (int i = 0; i < 2; ++i) {
        gl2lds16(kg[i] + (size_t)(it + 1) * 4096, lds + kdst[i] + po);
        gl2lds16(vg[i] + (it + 1) * 64, lds + vdst[i] + po);
      }
    }

    const bf16* Kl = lds + (h << 14) + bufo;
    f32x16 sa = {}, sb = {};
#pragma unroll
    for (int kc = 0; kc < 4; ++kc) {
      bf16x8 a0 = *(const bf16x8*)(Kl + raddr[kc]);
      bf16x8 a1 = *(const bf16x8*)(Kl + 2048 + raddr[kc]);
      sa = __builtin_amdgcn_mfma_f32_32x32x16_bf16(a0, aq[kc], sa, 0, 0, 0);
      sb = __builtin_amdgcn_mfma_f32_32x32x16_bf16(a1, aq[kc], sb, 0, 0, 0);
    }

    float rs = 0.f;
#pragma unroll
    for (int r = 0; r < 16; ++r) {
      sa[r] = __builtin_amdgcn_exp2f(sa[r]);
      sb[r] = __builtin_amdgcn_exp2f(sb[r]);
      rs += sa[r] + sb[r];
    }
    rs += __shfl_xor(rs, 32);
    l_ += rs;

    unsigned P2[2][8];
#pragma unroll
    for (int kq = 0; kq < 8; ++kq) {
      P2[0][kq] = pkbf(sa[2 * kq], sa[2 * kq + 1]);
      P2[1][kq] = pkbf(sb[2 * kq], sb[2 * kq + 1]);
    }

    const bf16* Vl = lds + (h << 14) + 8192 + bufo;
#pragma unroll
    for (int kk = 0; kk < 4; ++kk) {
      const int kmt = kk >> 1, kc = kk & 1;
      const unsigned mineA = hi ? P2[kmt][4 * kc + 2] : P2[kmt][4 * kc];
      const unsigned mineB = hi ? P2[kmt][4 * kc + 3] : P2[kmt][4 * kc + 1];
      const unsigned sendA = hi ? P2[kmt][4 * kc] : P2[kmt][4 * kc + 2];
      const unsigned sendB = hi ? P2[kmt][4 * kc + 1] : P2[kmt][4 * kc + 3];
      const unsigned ZA = (unsigned)__shfl_xor((int)sendA, 32);
      const unsigned ZB = (unsigned)__shfl_xor((int)sendB, 32);
      u32x4 bpi;
      bpi[0] = hi ? ZA : mineA;
      bpi[1] = hi ? ZB : mineB;
      bpi[2] = hi ? mineA : ZA;
      bpi[3] = hi ? mineB : ZB;
      const bf16x8 bp = __builtin_bit_cast(bf16x8, bpi);
#pragma unroll
      for (int emt = 0; emt < 2; ++emt) {
        bf16x8 av = *(const bf16x8*)(Vl + emt * 2048 + raddr[kk]);
        O[emt] = __builtin_amdgcn_mfma_f32_32x32x16_bf16(av, bp, O[emt], 0, 0, 0);
      }
    }
  }

  float* fl = (float*)lds;
  __syncthreads();
  if (w >= 4) {
#pragma unroll
    for (int emt = 0; emt < 2; ++emt)
#pragma unroll
      for (int r = 0; r < 16; ++r)
        fl[(w - 4) * 2048 + (emt * 16 + r) * 64 + lane] = O[emt][r];
    if (lane < 32) fl[8192 + (w - 4) * 32 + lane] = l_;
  }
  __syncthreads();
  if (w < 4) {
#pragma unroll
    for (int emt = 0; emt < 2; ++emt)
#pragma unroll
      for (int r = 0; r < 16; ++r)
        O[emt][r] += fl[w * 2048 + (emt * 16 + r) * 64 + lane];
    const float lsum = l_ + fl[8192 + w * 32 + lane31];
    const float inv = 1.0f / lsum;

    const int b = bh >> 4, hh = bh & 15;
    const int q = q0 + lane31;
    bf16* orow = attn + (size_t)(b * 2048 + q) * 1024 + hh * 64;
#pragma unroll
    for (int emt = 0; emt < 2; ++emt) {
#pragma unroll
      for (int kp = 0; kp < 8; ++kp) {
        const int r = 2 * kp;
        const int e0 = emt * 32 + (r & 3) + 8 * (kp >> 1) + 4 * hi;
        bf16x2 pr;
        pr[0] = (bf16)(O[emt][r] * inv);
        pr[1] = (bf16)(O[emt][r + 1] * inv);
        *(bf16x2*)(orow + e0) = pr;
      }
    }
  }
}

// ---------------- final GEMM: 128x64 tile, dbuf, fp32 out ----------------
__global__ __launch_bounds__(256) void k_gemm2(const bf16* __restrict__ A,
                                               const bf16* __restrict__ Bt,
                                               const float* __restrict__ bias,
                                               float* __restrict__ outp) {
  __shared__ __align__(16) bf16 Alds[2][4096];
  __shared__ __align__(16) bf16 Blds[2][2048];
  const int t = threadIdx.x;
  const int w = t >> 6;
  const int lane = t & 63;
  const int lane15 = lane & 15;
  const int quad = lane >> 4;
  const int mb = blockIdx.x, nb = blockIdx.y;

  const bf16* Ag0 = A + (size_t)(mb * 128 + lane) * 1024 + w * 8;
  const bf16* Ag1 = A + (size_t)(mb * 128 + 64 + lane) * 1024 + w * 8;
  const bf16* Bg = Bt + (size_t)(nb * 64 + lane) * 1024 + w * 8;
  const int a0 = w * 1024, a1 = w * 1024 + 512, b0 = w * 512;

  // prologue
  gl2lds16(Ag0, &Alds[0][a0]);
  gl2lds16(Ag1, &Alds[0][a1]);
  gl2lds16(Bg, &Blds[0][b0]);

  f32x4 acc[2][4] = {};

  for (int k0 = 0; k0 < 1024; k0 += 32) {
    const int b = (k0 >> 5) & 1;
    __syncthreads();
    if (k0 < 992) {
      gl2lds16(Ag0 + k0 + 32, &Alds[b ^ 1][a0]);
      gl2lds16(Ag1 + k0 + 32, &Alds[b ^ 1][a1]);
      gl2lds16(Bg + k0 + 32, &Blds[b ^ 1][b0]);
    }
    const bf16* Abuf = Alds[b];
    const bf16* Bbuf = Blds[b];
    bf16x8 af[2], bfr[4];
#pragma unroll
    for (int i = 0; i < 2; ++i)
      af[i] = *(const bf16x8*)(Abuf + (quad * 128 + w * 32 + i * 16 + lane15) * 8);
#pragma unroll
    for (int j = 0; j < 4; ++j)
      bfr[j] = *(const bf16x8*)(Bbuf + (quad * 64 + j * 16 + lane15) * 8);
#pragma unroll
    for (int i = 0; i < 2; ++i)
#pragma unroll
      for (int j = 0; j < 4; ++j)
        acc[i][j] = __builtin_amdgcn_mfma_f32_16x16x32_bf16(af[i], bfr[j], acc[i][j], 0, 0, 0);
  }

  const int mbase = mb * 128 + w * 32;
  const int nbase = nb * 64;
#pragma unroll
  for (int j = 0; j < 4; ++j) {
    const int n = nbase + j * 16 + lane15;
    const float bv = bias[n];
#pragma unroll
    for (int i = 0; i < 2; ++i) {
#pragma unroll
      for (int r = 0; r < 4; ++r) {
        const int m = mbase + i * 16 + quad * 4 + r;
        outp[(size_t)m * 1024 + n] = acc[i][j][r] + bv;
      }
    }
  }
}

// ---------------- launch ----------------
extern "C" void kernel_launch(void* const* d_in, const int* in_sizes, int n_in,
                              void* d_out, int out_size, void* d_ws, size_t ws_size,
                              hipStream_t stream) {
  (void)in_sizes; (void)n_in; (void)out_size; (void)ws_size;
  const float* q = (const float*)d_in[0];
  const float* k = (const float*)d_in[1];
  const float* v = (const float*)d_in[2];
  const float* Wq = (const float*)d_in[3];
  const float* bq = (const float*)d_in[4];
  const float* Wk = (const float*)d_in[5];
  const float* bk = (const float*)d_in[6];
  const float* Wv = (const float*)d_in[7];
  const float* bv = (const float*)d_in[8];
  const float* Wo = (const float*)d_in[9];
  const float* bo = (const float*)d_in[10];

  bf16* ws = (bf16*)d_ws;
  bf16* qkv = ws;                   // qb/kb/vb: 3 x 4M elems
  bf16* WqkvT = qkv + 12582912;     // 3 x 1M
  bf16* WoT = WqkvT + 3145728;      // 1M
  bf16* Qh = WoT + 1048576;         // 4M
  bf16* Kh = Qh + 4194304;          // 4M
  bf16* Vt = Kh + 4194304;          // 4M
  bf16* attnb = Vt + 4194304;       // 4M  (total 32M elems = 64 MiB)

  k_cvt<<<dim3(4096, 7), 256, 0, stream>>>(q, k, v, Wq, Wk, Wv, Wo, qkv, WqkvT, WoT);
  k_gemm_qkv<<<dim3(32, 24), 256, 0, stream>>>(qkv, WqkvT, bq, bk, bv, Qh, Kh, Vt);
  k_attn<<<dim3(16, 32), 512, 0, stream>>>(Qh, Kh, Vt, attnb);
  k_gemm2<<<dim3(32, 16), 256, 0, stream>>>(attnb, WoT, bo, (float*)d_out);
}